// Round 8
// baseline (13807.275 us; speedup 1.0000x reference)
//
#include <hip/hip_runtime.h>
#include <cstdint>
#include <cstddef>

// ---------------------------------------------------------------------------
// GumbelRNNGenerator, 2-kernels-per-step, LDS-bytes-minimized GEMMs (round 8).
// B=128, NOISE=128, H=512, V=5000, T=128 steps, all fp32.
// K1: 256 blk x 256 thr: stats + gi GEMM (4m x 3gate tiles, 2.3 B/FMA,
//     4-way K-striping) + gates + h-stats.
// K2: 208 blk x 256 thr: gh (32x128, 4x4/thread) + logits (same tile, o-BN
//     fold, gumbel, packed atomicMax). Full-K chains = bit-identical to R7.
// Softmax normalization batched once at the end.
// ---------------------------------------------------------------------------
#define B_SZ 128
#define NOISE_SZ 128
#define H 512
#define V_SZ 5000
#define BN_EPS 1e-5f

#define S1D 1099511627776.0   // 2^40
#define S2D 68719476736.0     // 2^36

// workspace offsets (floats)
#define SCRA_OFF 0            // [128][512] setup scratch
#define H_OFF    65536        // [128][512] hidden state
#define GH_OFF   131072       // [128][1536]
#define GIZ_OFF  327680       // [128][1536]
#define SH_OFF   524288       // ull[2][1024] h-stats (sum,sumsq) x 2 slots
#define SCRB_OFF 528896       // [128][512] setup scratch
#define AMX_OFF  594432       // ull[2][128*8] packed argmax keys, 64B-strided

// ------------------------------- Threefry ---------------------------------
__device__ __forceinline__ uint32_t rotl32(uint32_t v, int r) {
  return (v << r) | (v >> (32 - r));
}

__device__ __forceinline__ void threefry2x32(uint32_t k0, uint32_t k1,
                                             uint32_t x0, uint32_t x1,
                                             uint32_t& o0, uint32_t& o1) {
  uint32_t k2 = k0 ^ k1 ^ 0x1BD11BDAu;
  x0 += k0; x1 += k1;
#define TFR(r) { x0 += x1; x1 = rotl32(x1, (r)); x1 ^= x0; }
  TFR(13) TFR(15) TFR(26) TFR(6)
  x0 += k1; x1 += k2 + 1u;
  TFR(17) TFR(29) TFR(16) TFR(24)
  x0 += k2; x1 += k0 + 2u;
  TFR(13) TFR(15) TFR(26) TFR(6)
  x0 += k0; x1 += k1 + 3u;
  TFR(17) TFR(29) TFR(16) TFR(24)
  x0 += k1; x1 += k2 + 4u;
  TFR(13) TFR(15) TFR(26) TFR(6)
  x0 += k2; x1 += k0 + 5u;
#undef TFR
  o0 = x0; o1 = x1;
}

struct U2 { uint32_t a, b; };
constexpr U2 tf_c(uint32_t k0, uint32_t k1, uint32_t x0, uint32_t x1) {
  uint32_t k2 = k0 ^ k1 ^ 0x1BD11BDAu;
  x0 += k0; x1 += k1;
#define TFRC(r) { x0 += x1; x1 = (uint32_t)((x1 << (r)) | (x1 >> (32 - (r)))); x1 ^= x0; }
  TFRC(13) TFRC(15) TFRC(26) TFRC(6)
  x0 += k1; x1 += k2 + 1u;
  TFRC(17) TFRC(29) TFRC(16) TFRC(24)
  x0 += k2; x1 += k0 + 2u;
  TFRC(13) TFRC(15) TFRC(26) TFRC(6)
  x0 += k0; x1 += k1 + 3u;
  TFRC(17) TFRC(29) TFRC(16) TFRC(24)
  x0 += k1; x1 += k2 + 4u;
  TFRC(13) TFRC(15) TFRC(26) TFRC(6)
  x0 += k2; x1 += k0 + 5u;
#undef TFRC
  return U2{x0, x1};
}

struct SubKeys { uint32_t v[512]; };
constexpr SubKeys make_subkeys() {
  SubKeys s{};
  uint32_t k0 = 0u, k1 = 42u;
  for (int t = 0; t < 256; ++t) {
    U2 nk = tf_c(k0, k1, 0u, 0u);
    U2 sb = tf_c(k0, k1, 0u, 1u);
    s.v[2 * t] = sb.a; s.v[2 * t + 1] = sb.b;
    k0 = nk.a; k1 = nk.b;
  }
  return s;
}
__device__ __constant__ SubKeys SUBK = make_subkeys();

__device__ __forceinline__ float lrelu_(float x) { return x >= 0.f ? x : 0.2f * x; }
__device__ __forceinline__ float sigmoidf_(float x) {
  return (x >= 0.f) ? 1.f / (1.f + expf(-x)) : expf(x) / (1.f + expf(x));
}

// ------------------- GEMM 32x64 tile, 256 thr (setup only) -----------------
__device__ __forceinline__ void gemm32x64(
    const float* __restrict__ A, int lda,
    const float* __restrict__ W, int ldw, int K,
    int m0, int n0,
    const float* __restrict__ bias,
    bool relu,
    float* __restrict__ C, int ldc,
    float* smem) {
  float* As = smem;           // [32][38]
  float* Ws = smem + 1216;    // [32][68]
  const int tid = threadIdx.x;
  const int tn = tid & 15, tm = tid >> 4;
  const int amr = tid >> 3, aq = tid & 7;
  const int wnr = tid >> 2, wq = tid & 3;
  float acc[2][4] = {{0.f,0.f,0.f,0.f},{0.f,0.f,0.f,0.f}};
  for (int k0 = 0; k0 < K; k0 += 32) {
    const float4 av = *(const float4*)&A[(size_t)(m0 + amr) * lda + k0 + aq * 4];
    const float4 w0 = *(const float4*)&W[(size_t)(n0 + wnr) * ldw + k0 + wq * 4];
    const float4 w1 = *(const float4*)&W[(size_t)(n0 + wnr) * ldw + k0 + 16 + wq * 4];
    As[(aq * 4 + 0) * 38 + amr] = av.x;
    As[(aq * 4 + 1) * 38 + amr] = av.y;
    As[(aq * 4 + 2) * 38 + amr] = av.z;
    As[(aq * 4 + 3) * 38 + amr] = av.w;
    Ws[(wq * 4 + 0) * 68 + wnr] = w0.x;
    Ws[(wq * 4 + 1) * 68 + wnr] = w0.y;
    Ws[(wq * 4 + 2) * 68 + wnr] = w0.z;
    Ws[(wq * 4 + 3) * 68 + wnr] = w0.w;
    Ws[(16 + wq * 4 + 0) * 68 + wnr] = w1.x;
    Ws[(16 + wq * 4 + 1) * 68 + wnr] = w1.y;
    Ws[(16 + wq * 4 + 2) * 68 + wnr] = w1.z;
    Ws[(16 + wq * 4 + 3) * 68 + wnr] = w1.w;
    __syncthreads();
#pragma unroll
    for (int kk = 0; kk < 32; ++kk) {
      const float2 a2 = *(const float2*)&As[kk * 38 + tm * 2];
      const float4 b4 = *(const float4*)&Ws[kk * 68 + tn * 4];
      acc[0][0] = fmaf(a2.x, b4.x, acc[0][0]);
      acc[0][1] = fmaf(a2.x, b4.y, acc[0][1]);
      acc[0][2] = fmaf(a2.x, b4.z, acc[0][2]);
      acc[0][3] = fmaf(a2.x, b4.w, acc[0][3]);
      acc[1][0] = fmaf(a2.y, b4.x, acc[1][0]);
      acc[1][1] = fmaf(a2.y, b4.y, acc[1][1]);
      acc[1][2] = fmaf(a2.y, b4.z, acc[1][2]);
      acc[1][3] = fmaf(a2.y, b4.w, acc[1][3]);
    }
    __syncthreads();
  }
#pragma unroll
  for (int i = 0; i < 2; ++i) {
    const int m = m0 + tm * 2 + i;
#pragma unroll
    for (int j = 0; j < 4; ++j) {
      const int n = n0 + tn * 4 + j;
      float v = acc[i][j] + bias[n];
      if (relu) v = lrelu_(v);
      C[(size_t)m * ldc + n] = v;
    }
  }
}

// ----------------- BN over batch, 8 cols per 256-thr block -----------------
__device__ __forceinline__ void bn8(const float* __restrict__ in,
                                    const float* __restrict__ g,
                                    const float* __restrict__ be,
                                    float* __restrict__ outp,
                                    float* __restrict__ out2, int c0) {
  const int col = c0 + (threadIdx.x >> 5);
  const int r = threadIdx.x & 31;
  float x0 = in[(size_t)r * H + col];
  float x1 = in[(size_t)(r + 32) * H + col];
  float x2 = in[(size_t)(r + 64) * H + col];
  float x3 = in[(size_t)(r + 96) * H + col];
  float s = x0 + x1 + x2 + x3;
#pragma unroll
  for (int m = 16; m; m >>= 1) s += __shfl_xor(s, m);
  const float mean = s * (1.f / 128.f);
  const float d0 = x0 - mean, d1 = x1 - mean, d2 = x2 - mean, d3 = x3 - mean;
  float q = d0 * d0 + d1 * d1 + d2 * d2 + d3 * d3;
#pragma unroll
  for (int m = 16; m; m >>= 1) q += __shfl_xor(q, m);
  const float v = q * (1.f / 128.f);
  const float sd = sqrtf(v + BN_EPS);
  const float gc = g[col], bc = be[col];
  const float y0 = gc * d0 / sd + bc;
  const float y1 = gc * d1 / sd + bc;
  const float y2 = gc * d2 / sd + bc;
  const float y3 = gc * d3 / sd + bc;
  outp[(size_t)r * H + col] = y0;
  outp[(size_t)(r + 32) * H + col] = y1;
  outp[(size_t)(r + 64) * H + col] = y2;
  outp[(size_t)(r + 96) * H + col] = y3;
  if (out2) {
    out2[(size_t)r * H + col] = y0;
    out2[(size_t)(r + 32) * H + col] = y1;
    out2[(size_t)(r + 64) * H + col] = y2;
    out2[(size_t)(r + 96) * H + col] = y3;
  }
}

// ============================ setup kernels ================================

__global__ __launch_bounds__(256, 2) void k_z2h(const float* __restrict__ z,
                                                const float* __restrict__ W,
                                                const float* __restrict__ bias,
                                                float* __restrict__ fws) {
  __shared__ float smem[3392];
  gemm32x64(z, NOISE_SZ, W, NOISE_SZ, NOISE_SZ,
            ((int)blockIdx.x & 3) * 32, ((int)blockIdx.x >> 2) * 64,
            bias, true, fws + SCRA_OFF, H, smem);
}

__global__ __launch_bounds__(256, 2) void k_bn1(const float* __restrict__ g1,
                                                const float* __restrict__ be1,
                                                float* __restrict__ fws) {
  bn8(fws + SCRA_OFF, g1, be1, fws + SCRB_OFF, fws + H_OFF, (int)blockIdx.x * 8);
}

__global__ __launch_bounds__(256, 2) void k_bn2(const float* __restrict__ g2,
                                                const float* __restrict__ be2,
                                                float* __restrict__ fws) {
  bn8(fws + SCRB_OFF, g2 + H, be2 + H, fws + SCRB_OFF, nullptr, (int)blockIdx.x * 8);
}

__global__ __launch_bounds__(256, 2) void k_setup4(
    const float* __restrict__ W_ih, const float* __restrict__ b_ih,
    const float* __restrict__ W_hh, const float* __restrict__ b_hh,
    float* __restrict__ fws) {
  __shared__ float smem[3392];
  const int blk = blockIdx.x;
  if (blk < 96) {
    gemm32x64(fws + SCRB_OFF, H, W_ih + H, 2 * H, H,
              (blk & 3) * 32, (blk >> 2) * 64,
              b_ih, false, fws + GIZ_OFF, 1536, smem);
  } else if (blk < 192) {
    const int b2 = blk - 96;
    gemm32x64(fws + H_OFF, H, W_hh, H, H,
              (b2 & 3) * 32, (b2 >> 2) * 64,
              b_hh, false, fws + GH_OFF, 1536, smem);
  } else {
    unsigned long long* sH = (unsigned long long*)(fws + SH_OFF);
    for (int i = threadIdx.x; i < 1024; i += 256) sH[i] = 0ull;
  }
}

// ============================ K1: gates ====================================
// 256 blocks x 256 thr. Block = m-tile 32 (blk&3) x c-group 8 (blk>>2).
// Threads: kh = tid>>6 (K stripe), pos = tid&63 -> (ptm 0..7, ptc 0..7).
// Thread tile: 4 m-rows x 1 col x 3 gates; A b128 + packed-W b128 per kk.
#define K1_SCS 0
#define K1_SHS 512
#define K1_AS  1024   // [32 kk][36]
#define K1_WS  2176   // [32 kk][36] packed: [kk][tc*4+gate]
#define K1_PACC 3328  // [4 kh][64 pos][12]
#define K1_SRED 6400  // 512 long long (as 1024 floats)
#define K1_SIDX 7424  // 128 int (as 32 floats... need 128 ints = 128 floats)
// total 7552 floats

__global__ __launch_bounds__(256, 2) void k_gates(
    const float* __restrict__ emb,
    const float* __restrict__ g2, const float* __restrict__ be2,
    const float* __restrict__ W_ih,
    float* __restrict__ fws, int t) {
  __shared__ float smem[7552];
  float* scs = smem + K1_SCS;
  float* shs = smem + K1_SHS;
  float* As  = smem + K1_AS;
  float* Ws  = smem + K1_WS;
  float* pacc = smem + K1_PACC;
  long long* sred = (long long*)(smem + K1_SRED);
  int* sidx = (int*)(smem + K1_SIDX);

  const float* gi_z = fws + GIZ_OFF;
  const float* gh   = fws + GH_OFF;
  float* hbuf = fws + H_OFF;
  unsigned long long* statsH = (unsigned long long*)(fws + SH_OFF) + ((t & 1) ? 1024 : 0);
  unsigned long long* amax_prev = (unsigned long long*)(fws + AMX_OFF) + (((t + 1) & 1) ? 1024 : 0);
  unsigned long long* amax_cur  = (unsigned long long*)(fws + AMX_OFF) + ((t & 1) ? 1024 : 0);

  const int tid = threadIdx.x;
  const int blk = blockIdx.x;
  const int m0 = (blk & 3) * 32;
  const int c0 = (blk >> 2) * 8;
  const int kh = tid >> 6;
  const int pos = tid & 63;
  const int ptm = pos >> 3, ptc = pos & 7;

  if (tid < 128) {
    sidx[tid] = (t == 0) ? (V_SZ - 1)
                         : (int)(~(uint32_t)(amax_prev[tid * 8] & 0xFFFFFFFFull));
    if (blk == 0) amax_cur[tid * 8] = 0ull;
  }
  __syncthreads();

  // ---- si-BN column stats (2 cols/thread, fp64 — R4-validated order) ------
  {
    const int c = tid * 2;
    double s0 = 0.0, s1 = 0.0, q0 = 0.0, q1 = 0.0;
    for (int b = 0; b < 128; ++b) {
      const float* er = emb + (size_t)sidx[b] * H;
      const float2 v = *(const float2*)&er[c];
      const float x0 = lrelu_(v.x), x1 = lrelu_(v.y);
      s0 += x0; s1 += x1;
      q0 += (double)x0 * x0; q1 += (double)x1 * x1;
    }
    const double m0d = s0 * (1.0 / 128.0), m1d = s1 * (1.0 / 128.0);
    const double v0 = q0 * (1.0 / 128.0) - m0d * m0d;
    const double v1 = q1 * (1.0 / 128.0) - m1d * m1d;
    const float sd0 = sqrtf((float)v0 + BN_EPS);
    const float sd1 = sqrtf((float)v1 + BN_EPS);
    const float a0 = g2[c] / sd0, a1 = g2[c + 1] / sd1;
    scs[c] = a0; scs[c + 1] = a1;
    shs[c] = be2[c] - (float)m0d * a0;
    shs[c + 1] = be2[c + 1] - (float)m1d * a1;
  }
  __syncthreads();

  // ---- gi GEMM: 16 chunks of 32 k; kh-stripe kk in [kh*8, kh*8+8) ---------
  float aR[4] = {0.f,0.f,0.f,0.f};
  float aZ[4] = {0.f,0.f,0.f,0.f};
  float aN[4] = {0.f,0.f,0.f,0.f};
  const int am = tid >> 3, akq = tid & 7;       // A stager: row 0..31, k-quad
  const int wpr = tid >> 3, wkq = tid & 7;      // W stager (tid<192)
  const int wg = wpr >> 3, wtc = wpr & 7;
  for (int ch = 0; ch < 16; ++ch) {
    const int k0 = ch * 32;
    {
      const float4 rv = *(const float4*)&emb[(size_t)sidx[m0 + am] * H + k0 + akq * 4];
      const float4 s4 = *(const float4*)&scs[k0 + akq * 4];
      const float4 h4 = *(const float4*)&shs[k0 + akq * 4];
      As[(akq * 4 + 0) * 36 + am] = fmaf(lrelu_(rv.x), s4.x, h4.x);
      As[(akq * 4 + 1) * 36 + am] = fmaf(lrelu_(rv.y), s4.y, h4.y);
      As[(akq * 4 + 2) * 36 + am] = fmaf(lrelu_(rv.z), s4.z, h4.z);
      As[(akq * 4 + 3) * 36 + am] = fmaf(lrelu_(rv.w), s4.w, h4.w);
    }
    if (tid < 192) {
      const float4 w = *(const float4*)&W_ih[(size_t)(wg * 512 + c0 + wtc) * 1024 + k0 + wkq * 4];
      Ws[(wkq * 4 + 0) * 36 + wtc * 4 + wg] = w.x;
      Ws[(wkq * 4 + 1) * 36 + wtc * 4 + wg] = w.y;
      Ws[(wkq * 4 + 2) * 36 + wtc * 4 + wg] = w.z;
      Ws[(wkq * 4 + 3) * 36 + wtc * 4 + wg] = w.w;
    }
    __syncthreads();
    const int kb = kh * 8;
#pragma unroll
    for (int kk = kb; kk < kb + 8; ++kk) {
      const float4 a4 = *(const float4*)&As[kk * 36 + ptm * 4];
      const float4 w4 = *(const float4*)&Ws[kk * 36 + ptc * 4];
      aR[0] = fmaf(a4.x, w4.x, aR[0]);
      aR[1] = fmaf(a4.y, w4.x, aR[1]);
      aR[2] = fmaf(a4.z, w4.x, aR[2]);
      aR[3] = fmaf(a4.w, w4.x, aR[3]);
      aZ[0] = fmaf(a4.x, w4.y, aZ[0]);
      aZ[1] = fmaf(a4.y, w4.y, aZ[1]);
      aZ[2] = fmaf(a4.z, w4.y, aZ[2]);
      aZ[3] = fmaf(a4.w, w4.y, aZ[3]);
      aN[0] = fmaf(a4.x, w4.z, aN[0]);
      aN[1] = fmaf(a4.y, w4.z, aN[1]);
      aN[2] = fmaf(a4.z, w4.z, aN[2]);
      aN[3] = fmaf(a4.w, w4.z, aN[3]);
    }
    __syncthreads();
  }
  // ---- publish partials ----------------------------------------------------
  {
    float* p = pacc + (size_t)(kh * 64 + pos) * 12;
    p[0] = aR[0]; p[1] = aR[1]; p[2] = aR[2]; p[3] = aR[3];
    p[4] = aZ[0]; p[5] = aZ[1]; p[6] = aZ[2]; p[7] = aZ[3];
    p[8] = aN[0]; p[9] = aN[1]; p[10] = aN[2]; p[11] = aN[3];
  }
  __syncthreads();

  // ---- gates + h update (thread e -> element (m0 + e>>3, c0 + e&7)) --------
  {
    const int em = tid >> 3, ec = tid & 7;
    const int pe = (em >> 2) * 8 + ec;
    const int ie = em & 3;
    const float* p0 = pacc + (size_t)(0 * 64 + pe) * 12;
    const float* p1 = pacc + (size_t)(1 * 64 + pe) * 12;
    const float* p2 = pacc + (size_t)(2 * 64 + pe) * 12;
    const float* p3 = pacc + (size_t)(3 * 64 + pe) * 12;
    const float sR = ((p0[ie] + p1[ie]) + p2[ie]) + p3[ie];
    const float sZ = ((p0[4 + ie] + p1[4 + ie]) + p2[4 + ie]) + p3[4 + ie];
    const float sN = ((p0[8 + ie] + p1[8 + ie]) + p2[8 + ie]) + p3[8 + ie];
    const int m = m0 + em, c = c0 + ec;
    const size_t gb = (size_t)m * 1536;
    const float gv0 = sR + gi_z[gb + c];
    const float gv1 = sZ + gi_z[gb + 512 + c];
    const float gv2 = sN + gi_z[gb + 1024 + c];
    const float rr = sigmoidf_(gv0 + gh[gb + c]);
    const float zt = sigmoidf_(gv1 + gh[gb + 512 + c]);
    const float nn = tanhf(gv2 + rr * gh[gb + 1024 + c]);
    const size_t hix = (size_t)m * H + c;
    const float hold = hbuf[hix];
    const float hnew = (1.f - zt) * nn + zt * hold;
    hbuf[hix] = hnew;
    const float lx = lrelu_(hnew);
    sred[tid] = __double2ll_rn((double)lx * S1D);
    sred[256 + tid] = __double2ll_rn((double)lx * (double)lx * S2D);
  }
  __syncthreads();
  if (tid < 16) {
    const int c = tid & 7;
    long long s = 0;
    if (tid < 8) {
      for (int em = 0; em < 32; ++em) s += sred[em * 8 + c];
      atomicAdd(&statsH[c0 + c], (unsigned long long)s);
    } else {
      for (int em = 0; em < 32; ++em) s += sred[256 + em * 8 + c];
      atomicAdd(&statsH[512 + c0 + c], (unsigned long long)s);
    }
  }
}

// ============================ K2: logits + gh ==============================
// 208 blocks x 256 thr. blk<48: gh GEMM 32x128 (4x4/thread).
// blk>=48: logits 32x128 w/ o-BN fold, gumbel epilogue, packed atomicMax.
#define K2_AS  0      // [32 kk][36]
#define K2_WS  1152   // [32 kk][132]
#define K2_SCS 5376
#define K2_SHS 5888
// total 6400 floats

__device__ __forceinline__ void gemm32x128_body(
    const float* __restrict__ A,
    const float* __restrict__ scv, const float* __restrict__ shv, bool fold,
    const float* __restrict__ W, int nrows,
    int m0, int n0, float* As, float* Ws, float acc[4][4]) {
  const int tid = threadIdx.x;
  const int tx = tid & 31, ty = tid >> 5;
  const int am = tid >> 3, akq = tid & 7;
  for (int ch = 0; ch < 16; ++ch) {
    const int k0 = ch * 32;
    {
      float4 v = *(const float4*)&A[(size_t)(m0 + am) * 512 + k0 + akq * 4];
      if (fold) {
        const float4 s4 = *(const float4*)&scv[k0 + akq * 4];
        const float4 h4 = *(const float4*)&shv[k0 + akq * 4];
        v.x = fmaf(lrelu_(v.x), s4.x, h4.x);
        v.y = fmaf(lrelu_(v.y), s4.y, h4.y);
        v.z = fmaf(lrelu_(v.z), s4.z, h4.z);
        v.w = fmaf(lrelu_(v.w), s4.w, h4.w);
      }
      As[(akq * 4 + 0) * 36 + am] = v.x;
      As[(akq * 4 + 1) * 36 + am] = v.y;
      As[(akq * 4 + 2) * 36 + am] = v.z;
      As[(akq * 4 + 3) * 36 + am] = v.w;
    }
#pragma unroll
    for (int u = 0; u < 4; ++u) {
      const int i = tid + u * 256;
      const int wn = i >> 3, wkq = i & 7;
      float4 w = {0.f, 0.f, 0.f, 0.f};
      if (n0 + wn < nrows)
        w = *(const float4*)&W[(size_t)(n0 + wn) * 512 + k0 + wkq * 4];
      Ws[(wkq * 4 + 0) * 132 + wn] = w.x;
      Ws[(wkq * 4 + 1) * 132 + wn] = w.y;
      Ws[(wkq * 4 + 2) * 132 + wn] = w.z;
      Ws[(wkq * 4 + 3) * 132 + wn] = w.w;
    }
    __syncthreads();
#pragma unroll
    for (int kk = 0; kk < 32; ++kk) {
      const float4 a4 = *(const float4*)&As[kk * 36 + ty * 4];
      const float4 w4 = *(const float4*)&Ws[kk * 132 + tx * 4];
      acc[0][0] = fmaf(a4.x, w4.x, acc[0][0]);
      acc[0][1] = fmaf(a4.x, w4.y, acc[0][1]);
      acc[0][2] = fmaf(a4.x, w4.z, acc[0][2]);
      acc[0][3] = fmaf(a4.x, w4.w, acc[0][3]);
      acc[1][0] = fmaf(a4.y, w4.x, acc[1][0]);
      acc[1][1] = fmaf(a4.y, w4.y, acc[1][1]);
      acc[1][2] = fmaf(a4.y, w4.z, acc[1][2]);
      acc[1][3] = fmaf(a4.y, w4.w, acc[1][3]);
      acc[2][0] = fmaf(a4.z, w4.x, acc[2][0]);
      acc[2][1] = fmaf(a4.z, w4.y, acc[2][1]);
      acc[2][2] = fmaf(a4.z, w4.z, acc[2][2]);
      acc[2][3] = fmaf(a4.z, w4.w, acc[2][3]);
      acc[3][0] = fmaf(a4.w, w4.x, acc[3][0]);
      acc[3][1] = fmaf(a4.w, w4.y, acc[3][1]);
      acc[3][2] = fmaf(a4.w, w4.z, acc[3][2]);
      acc[3][3] = fmaf(a4.w, w4.w, acc[3][3]);
    }
    __syncthreads();
  }
}

__global__ __launch_bounds__(256, 2) void k_logits_gh(
    const float* __restrict__ W_h2o, const float* __restrict__ b_h2o,
    const float* __restrict__ W_hh, const float* __restrict__ b_hh,
    const float* __restrict__ g3, const float* __restrict__ be3,
    const float* __restrict__ temp_ptr, float* __restrict__ out,
    float* __restrict__ fws, int t, int T) {
  __shared__ float smem[6400];
  float* As = smem + K2_AS;
  float* Ws = smem + K2_WS;
  float* scs = smem + K2_SCS;
  float* shs = smem + K2_SHS;
  const int blk = blockIdx.x;
  const int tid = threadIdx.x;
  const int tx = tid & 31, ty = tid >> 5;
  unsigned long long* statsAll = (unsigned long long*)(fws + SH_OFF);
  float acc[4][4] = {{0,0,0,0},{0,0,0,0},{0,0,0,0},{0,0,0,0}};

  if (blk < 48) {
    if (blk == 0) {
      unsigned long long* othr = statsAll + (((t + 1) & 1) ? 1024 : 0);
      for (int i = tid; i < 1024; i += 256) othr[i] = 0ull;
    }
    const int m0 = (blk & 3) * 32, n0 = (blk >> 2) * 128;
    gemm32x128_body(fws + H_OFF, nullptr, nullptr, false,
                    W_hh, 1536, m0, n0, As, Ws, acc);
    float* ghp = fws + GH_OFF;
#pragma unroll
    for (int i = 0; i < 4; ++i) {
      const int m = m0 + ty * 4 + i;
      float4 v;
      v.x = acc[i][0] + b_hh[n0 + tx * 4 + 0];
      v.y = acc[i][1] + b_hh[n0 + tx * 4 + 1];
      v.z = acc[i][2] + b_hh[n0 + tx * 4 + 2];
      v.w = acc[i][3] + b_hh[n0 + tx * 4 + 3];
      *(float4*)&ghp[(size_t)m * 1536 + n0 + tx * 4] = v;
    }
    return;
  }

  // o-BN scale/shift from int64 stats (bit-identical to R7)
  const unsigned long long* sH = statsAll + ((t & 1) ? 1024 : 0);
  for (int c = tid; c < 512; c += 256) {
    const double sm = (double)(long long)sH[c] * (1.0 / (128.0 * S1D));
    const double e2 = (double)(long long)sH[512 + c] * (1.0 / (128.0 * S2D));
    const double var = e2 - sm * sm;
    const float sd = sqrtf((float)var + BN_EPS);
    const float a = g3[c] / sd;
    scs[c] = a; shs[c] = be3[c] - (float)sm * a;
  }
  __syncthreads();

  const int lg = blk - 48;
  const int m0 = (lg & 3) * 32, n0 = (lg >> 2) * 128;
  gemm32x128_body(fws + H_OFF, scs, shs, true,
                  W_h2o, V_SZ, m0, n0, As, Ws, acc);

  const float temp = temp_ptr[0];
  const uint32_t sk0 = SUBK.v[2 * t], sk1 = SUBK.v[2 * t + 1];
  const int nbase = n0 + tx * 4;
  unsigned long long bkey[4] = {0ull, 0ull, 0ull, 0ull};
#pragma unroll
  for (int i = 0; i < 4; ++i) {
    const int m = m0 + ty * 4 + i;
    float* rowp = out + ((size_t)m * T + t) * V_SZ;
    float yv[4];
#pragma unroll
    for (int j = 0; j < 4; ++j) {
      const int n = nbase + j;
      if (n < V_SZ) {
        const float logit = acc[i][j] + b_h2o[n];
        uint32_t r0, r1;
        threefry2x32(sk0, sk1, 0u, (uint32_t)(m * V_SZ + n), r0, r1);
        const uint32_t bits = r0 ^ r1;
        const float f = __uint_as_float((bits >> 9) | 0x3f800000u) - 1.0f;
        const float u = fmaxf(1e-20f, f + 1e-20f);
        const float gum = -logf(-logf(u));
        const float y = (logit + gum) / temp;
        yv[j] = y;
        uint32_t ub = __float_as_uint(y);
        ub = (ub & 0x80000000u) ? ~ub : (ub | 0x80000000u);
        const unsigned long long key =
            ((unsigned long long)ub << 32) | (unsigned long long)(~(uint32_t)n);
        if (key > bkey[i]) bkey[i] = key;
      } else {
        yv[j] = 0.f;
      }
    }
    if (nbase + 3 < V_SZ) {
      float4 v4; v4.x = yv[0]; v4.y = yv[1]; v4.z = yv[2]; v4.w = yv[3];
      *(float4*)&rowp[nbase] = v4;
    } else {
#pragma unroll
      for (int j = 0; j < 4; ++j)
        if (nbase + j < V_SZ) rowp[nbase + j] = yv[j];
    }
  }
#pragma unroll
  for (int mk = 1; mk < 32; mk <<= 1) {
#pragma unroll
    for (int i = 0; i < 4; ++i) {
      const unsigned long long o = __shfl_xor(bkey[i], mk);
      if (o > bkey[i]) bkey[i] = o;
    }
  }
  if (tx == 0) {
    unsigned long long* am = (unsigned long long*)(fws + AMX_OFF) + ((t & 1) ? 1024 : 0);
#pragma unroll
    for (int i = 0; i < 4; ++i)
      atomicMax(&am[(m0 + ty * 4 + i) * 8], bkey[i]);
  }
}

// final: batched softmax normalization of all B*T rows (in place in out)
__global__ __launch_bounds__(256, 2) void k_soft(float* __restrict__ out, int T) {
  __shared__ float sy[V_SZ];
  __shared__ float red[256];
  const int bid = blockIdx.x;
  const int b = bid / T, t = bid - b * T;
  const int tid = threadIdx.x;
  float* row = out + ((size_t)b * T + t) * V_SZ;

  float lmax = -3.4e38f;
  for (int j = tid; j < V_SZ; j += 256) {
    const float y = row[j];
    sy[j] = y;
    lmax = fmaxf(lmax, y);
  }
  red[tid] = lmax; __syncthreads();
#pragma unroll
  for (int s = 128; s > 0; s >>= 1) {
    if (tid < s) red[tid] = fmaxf(red[tid], red[tid + s]);
    __syncthreads();
  }
  const float m = red[0];
  __syncthreads();

  float lsum = 0.f;
  for (int j = tid; j < V_SZ; j += 256) {
    const float e = expf(sy[j] - m); sy[j] = e; lsum += e;
  }
  red[tid] = lsum; __syncthreads();
#pragma unroll
  for (int s = 128; s > 0; s >>= 1) {
    if (tid < s) red[tid] += red[tid + s];
    __syncthreads();
  }
  const float S = red[0];
  __syncthreads();

  for (int j = tid; j < V_SZ; j += 256) row[j] = sy[j] / S;
}

// ---------------------------------------------------------------------------
extern "C" void kernel_launch(void* const* d_in, const int* in_sizes, int n_in,
                              void* d_out, int out_size, void* d_ws, size_t ws_size,
                              hipStream_t stream) {
  const float* z     = (const float*)d_in[0];
  const float* temp  = (const float*)d_in[1];
  const float* W_z2h = (const float*)d_in[3];
  const float* b_z2h = (const float*)d_in[4];
  const float* g1    = (const float*)d_in[5];
  const float* be1   = (const float*)d_in[6];
  const float* emb   = (const float*)d_in[7];
  const float* g2    = (const float*)d_in[8];
  const float* be2   = (const float*)d_in[9];
  const float* W_ih  = (const float*)d_in[10];
  const float* b_ih  = (const float*)d_in[11];
  const float* W_hh  = (const float*)d_in[12];
  const float* b_hh  = (const float*)d_in[13];
  const float* g3    = (const float*)d_in[14];
  const float* be3   = (const float*)d_in[15];
  const float* W_h2o = (const float*)d_in[16];
  const float* b_h2o = (const float*)d_in[17];
  float* out = (float*)d_out;
  float* fws = (float*)d_ws;
  const int T = out_size / (B_SZ * V_SZ);   // 128

  // ---- setup ----
  k_z2h<<<32, 256, 0, stream>>>(z, W_z2h, b_z2h, fws);
  k_bn1<<<64, 256, 0, stream>>>(g1, be1, fws);
  k_bn2<<<64, 256, 0, stream>>>(g2, be2, fws);
  k_setup4<<<193, 256, 0, stream>>>(W_ih, b_ih, W_hh, b_hh, fws);

  // ---- steps: 2 kernels each ----
  for (int t = 0; t < T; ++t) {
    k_gates<<<256, 256, 0, stream>>>(emb, g2, be2, W_ih, fws, t);
    k_logits_gh<<<208, 256, 0, stream>>>(W_h2o, b_h2o, W_hh, b_hh, g3, be3,
                                         temp, out, fws, t, T);
  }

  // ---- batched softmax normalization ----
  k_soft<<<B_SZ * T, 256, 0, stream>>>(out, T);
}

// Round 9
// 8414.700 us; speedup vs baseline: 1.6409x; 1.6409x over previous
//
#include <hip/hip_runtime.h>
#include <cstdint>
#include <cstddef>

// ---------------------------------------------------------------------------
// GumbelRNNGenerator, round 9 = round 6 (best, 9.95 ms) with ONE change:
// K2's logits retiled 16x80 (1m x 5n) -> 32x64 (2m x 4n, gemm32x64 shape),
// halving K2's LDS-pipe cycles. Everything else verbatim round 6.
// ---------------------------------------------------------------------------
#define B_SZ 128
#define NOISE_SZ 128
#define H 512
#define V_SZ 5000
#define BN_EPS 1e-5f

#define S1D 1099511627776.0   // 2^40
#define S2D 68719476736.0     // 2^36

// workspace offsets (floats)
#define SCRA_OFF 0            // [128][512] setup scratch
#define H_OFF    65536        // [128][512] hidden state
#define GH_OFF   131072       // [128][1536]
#define GIZ_OFF  327680       // [128][1536]
#define SH_OFF   524288       // ull[2][1024] h-stats (sum,sumsq) x 2 slots
#define SCRB_OFF 528896       // [128][512] setup scratch
#define AMX_OFF  594432       // ull[2][128*8] packed argmax keys, 64B-strided

// ------------------------------- Threefry ---------------------------------
__device__ __forceinline__ uint32_t rotl32(uint32_t v, int r) {
  return (v << r) | (v >> (32 - r));
}

__device__ __forceinline__ void threefry2x32(uint32_t k0, uint32_t k1,
                                             uint32_t x0, uint32_t x1,
                                             uint32_t& o0, uint32_t& o1) {
  uint32_t k2 = k0 ^ k1 ^ 0x1BD11BDAu;
  x0 += k0; x1 += k1;
#define TFR(r) { x0 += x1; x1 = rotl32(x1, (r)); x1 ^= x0; }
  TFR(13) TFR(15) TFR(26) TFR(6)
  x0 += k1; x1 += k2 + 1u;
  TFR(17) TFR(29) TFR(16) TFR(24)
  x0 += k2; x1 += k0 + 2u;
  TFR(13) TFR(15) TFR(26) TFR(6)
  x0 += k0; x1 += k1 + 3u;
  TFR(17) TFR(29) TFR(16) TFR(24)
  x0 += k1; x1 += k2 + 4u;
  TFR(13) TFR(15) TFR(26) TFR(6)
  x0 += k2; x1 += k0 + 5u;
#undef TFR
  o0 = x0; o1 = x1;
}

struct U2 { uint32_t a, b; };
constexpr U2 tf_c(uint32_t k0, uint32_t k1, uint32_t x0, uint32_t x1) {
  uint32_t k2 = k0 ^ k1 ^ 0x1BD11BDAu;
  x0 += k0; x1 += k1;
#define TFRC(r) { x0 += x1; x1 = (uint32_t)((x1 << (r)) | (x1 >> (32 - (r)))); x1 ^= x0; }
  TFRC(13) TFRC(15) TFRC(26) TFRC(6)
  x0 += k1; x1 += k2 + 1u;
  TFRC(17) TFRC(29) TFRC(16) TFRC(24)
  x0 += k2; x1 += k0 + 2u;
  TFRC(13) TFRC(15) TFRC(26) TFRC(6)
  x0 += k0; x1 += k1 + 3u;
  TFRC(17) TFRC(29) TFRC(16) TFRC(24)
  x0 += k1; x1 += k2 + 4u;
  TFRC(13) TFRC(15) TFRC(26) TFRC(6)
  x0 += k2; x1 += k0 + 5u;
#undef TFRC
  return U2{x0, x1};
}

struct SubKeys { uint32_t v[512]; };
constexpr SubKeys make_subkeys() {
  SubKeys s{};
  uint32_t k0 = 0u, k1 = 42u;
  for (int t = 0; t < 256; ++t) {
    U2 nk = tf_c(k0, k1, 0u, 0u);
    U2 sb = tf_c(k0, k1, 0u, 1u);
    s.v[2 * t] = sb.a; s.v[2 * t + 1] = sb.b;
    k0 = nk.a; k1 = nk.b;
  }
  return s;
}
__device__ __constant__ SubKeys SUBK = make_subkeys();

__device__ __forceinline__ float lrelu_(float x) { return x >= 0.f ? x : 0.2f * x; }
__device__ __forceinline__ float sigmoidf_(float x) {
  return (x >= 0.f) ? 1.f / (1.f + expf(-x)) : expf(x) / (1.f + expf(x));
}

// ------------------------- GEMM 32x64 tile (device fn) ---------------------
__device__ __forceinline__ void gemm32x64(
    const float* __restrict__ A, int lda,
    const float* __restrict__ W, int ldw, int K,
    int m0, int n0,
    const float* __restrict__ bias,
    bool relu,
    float* __restrict__ C, int ldc,
    float* smem) {
  float* As = smem;           // [32][38]
  float* Ws = smem + 1216;    // [32][68]
  const int tid = threadIdx.x;
  const int tn = tid & 15, tm = tid >> 4;
  const int amr = tid >> 3, aq = tid & 7;
  const int wnr = tid >> 2, wq = tid & 3;
  float acc[2][4] = {{0.f,0.f,0.f,0.f},{0.f,0.f,0.f,0.f}};
  for (int k0 = 0; k0 < K; k0 += 32) {
    const float4 av = *(const float4*)&A[(size_t)(m0 + amr) * lda + k0 + aq * 4];
    const float4 w0 = *(const float4*)&W[(size_t)(n0 + wnr) * ldw + k0 + wq * 4];
    const float4 w1 = *(const float4*)&W[(size_t)(n0 + wnr) * ldw + k0 + 16 + wq * 4];
    As[(aq * 4 + 0) * 38 + amr] = av.x;
    As[(aq * 4 + 1) * 38 + amr] = av.y;
    As[(aq * 4 + 2) * 38 + amr] = av.z;
    As[(aq * 4 + 3) * 38 + amr] = av.w;
    Ws[(wq * 4 + 0) * 68 + wnr] = w0.x;
    Ws[(wq * 4 + 1) * 68 + wnr] = w0.y;
    Ws[(wq * 4 + 2) * 68 + wnr] = w0.z;
    Ws[(wq * 4 + 3) * 68 + wnr] = w0.w;
    Ws[(16 + wq * 4 + 0) * 68 + wnr] = w1.x;
    Ws[(16 + wq * 4 + 1) * 68 + wnr] = w1.y;
    Ws[(16 + wq * 4 + 2) * 68 + wnr] = w1.z;
    Ws[(16 + wq * 4 + 3) * 68 + wnr] = w1.w;
    __syncthreads();
#pragma unroll
    for (int kk = 0; kk < 32; ++kk) {
      const float2 a2 = *(const float2*)&As[kk * 38 + tm * 2];
      const float4 b4 = *(const float4*)&Ws[kk * 68 + tn * 4];
      acc[0][0] = fmaf(a2.x, b4.x, acc[0][0]);
      acc[0][1] = fmaf(a2.x, b4.y, acc[0][1]);
      acc[0][2] = fmaf(a2.x, b4.z, acc[0][2]);
      acc[0][3] = fmaf(a2.x, b4.w, acc[0][3]);
      acc[1][0] = fmaf(a2.y, b4.x, acc[1][0]);
      acc[1][1] = fmaf(a2.y, b4.y, acc[1][1]);
      acc[1][2] = fmaf(a2.y, b4.z, acc[1][2]);
      acc[1][3] = fmaf(a2.y, b4.w, acc[1][3]);
    }
    __syncthreads();
  }
#pragma unroll
  for (int i = 0; i < 2; ++i) {
    const int m = m0 + tm * 2 + i;
#pragma unroll
    for (int j = 0; j < 4; ++j) {
      const int n = n0 + tn * 4 + j;
      float v = acc[i][j] + bias[n];
      if (relu) v = lrelu_(v);
      C[(size_t)m * ldc + n] = v;
    }
  }
}

// ----------------- BN over batch, 8 cols per 256-thr block -----------------
__device__ __forceinline__ void bn8(const float* __restrict__ in,
                                    const float* __restrict__ g,
                                    const float* __restrict__ be,
                                    float* __restrict__ outp,
                                    float* __restrict__ out2, int c0) {
  const int col = c0 + (threadIdx.x >> 5);
  const int r = threadIdx.x & 31;
  float x0 = in[(size_t)r * H + col];
  float x1 = in[(size_t)(r + 32) * H + col];
  float x2 = in[(size_t)(r + 64) * H + col];
  float x3 = in[(size_t)(r + 96) * H + col];
  float s = x0 + x1 + x2 + x3;
#pragma unroll
  for (int m = 16; m; m >>= 1) s += __shfl_xor(s, m);
  const float mean = s * (1.f / 128.f);
  const float d0 = x0 - mean, d1 = x1 - mean, d2 = x2 - mean, d3 = x3 - mean;
  float q = d0 * d0 + d1 * d1 + d2 * d2 + d3 * d3;
#pragma unroll
  for (int m = 16; m; m >>= 1) q += __shfl_xor(q, m);
  const float v = q * (1.f / 128.f);
  const float sd = sqrtf(v + BN_EPS);
  const float gc = g[col], bc = be[col];
  const float y0 = gc * d0 / sd + bc;
  const float y1 = gc * d1 / sd + bc;
  const float y2 = gc * d2 / sd + bc;
  const float y3 = gc * d3 / sd + bc;
  outp[(size_t)r * H + col] = y0;
  outp[(size_t)(r + 32) * H + col] = y1;
  outp[(size_t)(r + 64) * H + col] = y2;
  outp[(size_t)(r + 96) * H + col] = y3;
  if (out2) {
    out2[(size_t)r * H + col] = y0;
    out2[(size_t)(r + 32) * H + col] = y1;
    out2[(size_t)(r + 64) * H + col] = y2;
    out2[(size_t)(r + 96) * H + col] = y3;
  }
}

// ============================ setup kernels ================================

__global__ __launch_bounds__(256, 2) void k_z2h(const float* __restrict__ z,
                                                const float* __restrict__ W,
                                                const float* __restrict__ bias,
                                                float* __restrict__ fws) {
  __shared__ float smem[3392];
  gemm32x64(z, NOISE_SZ, W, NOISE_SZ, NOISE_SZ,
            ((int)blockIdx.x & 3) * 32, ((int)blockIdx.x >> 2) * 64,
            bias, true, fws + SCRA_OFF, H, smem);
}

__global__ __launch_bounds__(256, 2) void k_bn1(const float* __restrict__ g1,
                                                const float* __restrict__ be1,
                                                float* __restrict__ fws) {
  bn8(fws + SCRA_OFF, g1, be1, fws + SCRB_OFF, fws + H_OFF, (int)blockIdx.x * 8);
}

__global__ __launch_bounds__(256, 2) void k_bn2(const float* __restrict__ g2,
                                                const float* __restrict__ be2,
                                                float* __restrict__ fws) {
  bn8(fws + SCRB_OFF, g2 + H, be2 + H, fws + SCRB_OFF, nullptr, (int)blockIdx.x * 8);
}

__global__ __launch_bounds__(256, 2) void k_setup4(
    const float* __restrict__ W_ih, const float* __restrict__ b_ih,
    const float* __restrict__ W_hh, const float* __restrict__ b_hh,
    float* __restrict__ fws) {
  __shared__ float smem[3392];
  const int blk = blockIdx.x;
  if (blk < 96) {
    gemm32x64(fws + SCRB_OFF, H, W_ih + H, 2 * H, H,
              (blk & 3) * 32, (blk >> 2) * 64,
              b_ih, false, fws + GIZ_OFF, 1536, smem);
  } else if (blk < 192) {
    const int b2 = blk - 96;
    gemm32x64(fws + H_OFF, H, W_hh, H, H,
              (b2 & 3) * 32, (b2 >> 2) * 64,
              b_hh, false, fws + GH_OFF, 1536, smem);
  } else {
    unsigned long long* sH = (unsigned long long*)(fws + SH_OFF);
    for (int i = threadIdx.x; i < 1024; i += 256) sH[i] = 0ull;
  }
}

// K1: 256 blocks x 512 threads, split-K (round-6 verbatim).
__global__ __launch_bounds__(512, 2) void k_gates(
    const float* __restrict__ emb,
    const float* __restrict__ g2, const float* __restrict__ be2,
    const float* __restrict__ W_ih,
    float* __restrict__ fws, int t) {
  __shared__ float scs[512], shs[512];
  __shared__ int sidx[128];
  __shared__ float As[2 * 544];    // per-half [32][17]
  __shared__ float Ws[2 * 1664];   // per-half [32][52]
  __shared__ float sgi[2 * 800];   // per-half [16][50]
  const float* gi_z = fws + GIZ_OFF;
  const float* gh   = fws + GH_OFF;
  float* hbuf = fws + H_OFF;
  unsigned long long* statsH = (unsigned long long*)(fws + SH_OFF) + ((t & 1) ? 1024 : 0);
  unsigned long long* amax_prev = (unsigned long long*)(fws + AMX_OFF) + (((t + 1) & 1) ? 1024 : 0);
  unsigned long long* amax_cur  = (unsigned long long*)(fws + AMX_OFF) + ((t & 1) ? 1024 : 0);
  const int tid = threadIdx.x;
  const int kh = tid >> 8;         // K-half
  const int tt = tid & 255;
  const int blk = blockIdx.x;
  const int m0 = (blk >> 5) * 16;
  const int c0 = (blk & 31) * 16;

  if (tid < 128) {
    sidx[tid] = (t == 0) ? (V_SZ - 1)
                         : (int)(~(uint32_t)(amax_prev[tid * 8] & 0xFFFFFFFFull));
    if (blk == 0) amax_cur[tid * 8] = 0ull;
  }
  __syncthreads();

  // ---- si-BN column stats (1 col/thread, coalesced row reads, fp64) -------
  {
    double s = 0.0, q = 0.0;
    for (int b = 0; b < 128; ++b) {
      const float x = lrelu_(emb[(size_t)sidx[b] * H + tid]);
      s += x; q += (double)x * x;
    }
    const double md = s * (1.0 / 128.0);
    const double vd = q * (1.0 / 128.0) - md * md;
    const float sd = sqrtf((float)vd + BN_EPS);
    const float a = g2[tid] / sd;
    scs[tid] = a;
    shs[tid] = be2[tid] - (float)md * a;
  }
  __syncthreads();

  // ---- gi tile: 16 rows x 48 gate-cols, split-K (each half K=256) ---------
  const int tm = tt >> 4, tn = tt & 15;
  const int amr = tt >> 3, aq = tt & 7;
  float* Ash = As + kh * 544;
  float* Wsh = Ws + kh * 1664;
  float acc0 = 0.f, acc1 = 0.f, acc2 = 0.f;
  for (int k0i = 0; k0i < 8; ++k0i) {
    const int k0 = kh * 256 + k0i * 32;
    if (tt < 128) {
      const float4 rv = *(const float4*)&emb[(size_t)sidx[m0 + amr] * H + k0 + aq * 4];
      const float4 a4 = *(const float4*)&scs[k0 + aq * 4];
      const float4 h4 = *(const float4*)&shs[k0 + aq * 4];
      float4 av;
      av.x = fmaf(lrelu_(rv.x), a4.x, h4.x);
      av.y = fmaf(lrelu_(rv.y), a4.y, h4.y);
      av.z = fmaf(lrelu_(rv.z), a4.z, h4.z);
      av.w = fmaf(lrelu_(rv.w), a4.w, h4.w);
      Ash[(aq * 4 + 0) * 17 + amr] = av.x;
      Ash[(aq * 4 + 1) * 17 + amr] = av.y;
      Ash[(aq * 4 + 2) * 17 + amr] = av.z;
      Ash[(aq * 4 + 3) * 17 + amr] = av.w;
    }
    {
      int i = tt;
#pragma unroll
      for (int rep = 0; rep < 2; ++rep) {
        if (i < 384) {
          const int wr = i >> 3, wq = i & 7;
          const int wrow = (wr < 16) ? (c0 + wr)
                         : (wr < 32) ? (512 + c0 + wr - 16)
                                     : (1024 + c0 + wr - 32);
          const float4 w = *(const float4*)&W_ih[(size_t)wrow * 1024 + k0 + wq * 4];
          Wsh[(wq * 4 + 0) * 52 + wr] = w.x;
          Wsh[(wq * 4 + 1) * 52 + wr] = w.y;
          Wsh[(wq * 4 + 2) * 52 + wr] = w.z;
          Wsh[(wq * 4 + 3) * 52 + wr] = w.w;
        }
        i += 256;
      }
    }
    __syncthreads();
#pragma unroll
    for (int kk = 0; kk < 32; ++kk) {
      const float a = Ash[kk * 17 + tm];
      acc0 = fmaf(a, Wsh[kk * 52 + tn], acc0);
      acc1 = fmaf(a, Wsh[kk * 52 + 16 + tn], acc1);
      acc2 = fmaf(a, Wsh[kk * 52 + 32 + tn], acc2);
    }
    __syncthreads();
  }
  sgi[kh * 800 + tm * 50 + tn]      = acc0;
  sgi[kh * 800 + tm * 50 + 16 + tn] = acc1;
  sgi[kh * 800 + tm * 50 + 32 + tn] = acc2;
  __syncthreads();

  // ---- gates + h update + stats partials (half 0 only) ---------------------
  long long* sred = (long long*)Ws;
  if (kh == 0) {
    const size_t gzb = (size_t)(m0 + tm) * 1536;
    const size_t ghb = gzb;
    const float gv0 = (sgi[tm * 50 + tn] + sgi[800 + tm * 50 + tn]) + gi_z[gzb + c0 + tn];
    const float gv1 = (sgi[tm * 50 + 16 + tn] + sgi[800 + tm * 50 + 16 + tn]) + gi_z[gzb + 512 + c0 + tn];
    const float gv2 = (sgi[tm * 50 + 32 + tn] + sgi[800 + tm * 50 + 32 + tn]) + gi_z[gzb + 1024 + c0 + tn];
    const float rr = sigmoidf_(gv0 + gh[ghb + c0 + tn]);
    const float zt = sigmoidf_(gv1 + gh[ghb + 512 + c0 + tn]);
    const float nn = tanhf(gv2 + rr * gh[ghb + 1024 + c0 + tn]);
    const size_t hix = (size_t)(m0 + tm) * H + c0 + tn;
    const float hold = hbuf[hix];
    const float hnew = (1.f - zt) * nn + zt * hold;
    hbuf[hix] = hnew;
    const float lx = lrelu_(hnew);
    sred[tt] = __double2ll_rn((double)lx * S1D);
    sred[256 + tt] = __double2ll_rn((double)lx * (double)lx * S2D);
  }
  __syncthreads();
  if (tid < 32) {
    const int c = tid & 15;
    long long s = 0;
    if (tid < 16) {
      for (int b = 0; b < 16; ++b) s += sred[c + 16 * b];
      atomicAdd(&statsH[c0 + c], (unsigned long long)s);
    } else {
      for (int b = 0; b < 16; ++b) s += sred[256 + c + 16 * b];
      atomicAdd(&statsH[512 + c0 + c], (unsigned long long)s);
    }
  }
}

// K2: 412 blocks x 256 thr. blk<96: gh ride-along (+stats zero on blk 0);
// blk>=96: logits 32x64 tile (2m x 4n / thread), o-BN fold, gumbel, atomicMax.
__global__ __launch_bounds__(256, 2) void k_logits_gh(
    const float* __restrict__ W_h2o, const float* __restrict__ b_h2o,
    const float* __restrict__ W_hh, const float* __restrict__ b_hh,
    const float* __restrict__ g3, const float* __restrict__ be3,
    const float* __restrict__ temp_ptr, float* __restrict__ out,
    float* __restrict__ fws, int t, int T) {
  __shared__ float smem[4416];
  const int blk = blockIdx.x;
  const int tid = threadIdx.x;
  unsigned long long* statsAll = (unsigned long long*)(fws + SH_OFF);
  if (blk < 96) {
    if (blk == 0) {
      unsigned long long* othr = statsAll + (((t + 1) & 1) ? 1024 : 0);
      for (int i = tid; i < 1024; i += 256) othr[i] = 0ull;
    }
    gemm32x64(fws + H_OFF, H, W_hh, H, H,
              (blk & 3) * 32, (blk >> 2) * 64,
              b_hh, false, fws + GH_OFF, 1536, smem);
    return;
  }
  float* As = smem;            // [32][38]
  float* Ws = smem + 1216;     // [32][68]
  float* scs = smem + 3392;    // [512]
  float* shs = smem + 3904;    // [512]
  const unsigned long long* sH = statsAll + ((t & 1) ? 1024 : 0);
  for (int c = tid; c < 512; c += 256) {
    const double sm = (double)(long long)sH[c] * (1.0 / (128.0 * S1D));
    const double e2 = (double)(long long)sH[512 + c] * (1.0 / (128.0 * S2D));
    const double var = e2 - sm * sm;
    const float sd = sqrtf((float)var + BN_EPS);
    const float a = g3[c] / sd;
    scs[c] = a; shs[c] = be3[c] - (float)sm * a;
  }
  __syncthreads();

  const float* hbuf = fws + H_OFF;
  const int lg = blk - 96;                 // 0..315
  const int m0 = (lg & 3) * 32, n0 = (lg >> 2) * 64;
  const int tn = tid & 15, tm = tid >> 4;
  const int amr = tid >> 3, aq = tid & 7;
  const int wnr = tid >> 2, wq = tid & 3;
  float acc[2][4] = {{0.f,0.f,0.f,0.f},{0.f,0.f,0.f,0.f}};
  for (int k0 = 0; k0 < 512; k0 += 32) {
    // A stage with o-BN fold (32 rows x 32 k)
    {
      const float4 hv = *(const float4*)&hbuf[(size_t)(m0 + amr) * 512 + k0 + aq * 4];
      const float4 a4 = *(const float4*)&scs[k0 + aq * 4];
      const float4 c4 = *(const float4*)&shs[k0 + aq * 4];
      As[(aq * 4 + 0) * 38 + amr] = fmaf(lrelu_(hv.x), a4.x, c4.x);
      As[(aq * 4 + 1) * 38 + amr] = fmaf(lrelu_(hv.y), a4.y, c4.y);
      As[(aq * 4 + 2) * 38 + amr] = fmaf(lrelu_(hv.z), a4.z, c4.z);
      As[(aq * 4 + 3) * 38 + amr] = fmaf(lrelu_(hv.w), a4.w, c4.w);
    }
    // W stage (64 rows x 32 k), guarded at V boundary
    {
      float4 w0 = {0.f,0.f,0.f,0.f}, w1 = {0.f,0.f,0.f,0.f};
      if (n0 + wnr < V_SZ) {
        w0 = *(const float4*)&W_h2o[(size_t)(n0 + wnr) * 512 + k0 + wq * 4];
        w1 = *(const float4*)&W_h2o[(size_t)(n0 + wnr) * 512 + k0 + 16 + wq * 4];
      }
      Ws[(wq * 4 + 0) * 68 + wnr] = w0.x;
      Ws[(wq * 4 + 1) * 68 + wnr] = w0.y;
      Ws[(wq * 4 + 2) * 68 + wnr] = w0.z;
      Ws[(wq * 4 + 3) * 68 + wnr] = w0.w;
      Ws[(16 + wq * 4 + 0) * 68 + wnr] = w1.x;
      Ws[(16 + wq * 4 + 1) * 68 + wnr] = w1.y;
      Ws[(16 + wq * 4 + 2) * 68 + wnr] = w1.z;
      Ws[(16 + wq * 4 + 3) * 68 + wnr] = w1.w;
    }
    __syncthreads();
#pragma unroll
    for (int kk = 0; kk < 32; ++kk) {
      const float2 a2 = *(const float2*)&As[kk * 38 + tm * 2];
      const float4 b4 = *(const float4*)&Ws[kk * 68 + tn * 4];
      acc[0][0] = fmaf(a2.x, b4.x, acc[0][0]);
      acc[0][1] = fmaf(a2.x, b4.y, acc[0][1]);
      acc[0][2] = fmaf(a2.x, b4.z, acc[0][2]);
      acc[0][3] = fmaf(a2.x, b4.w, acc[0][3]);
      acc[1][0] = fmaf(a2.y, b4.x, acc[1][0]);
      acc[1][1] = fmaf(a2.y, b4.y, acc[1][1]);
      acc[1][2] = fmaf(a2.y, b4.z, acc[1][2]);
      acc[1][3] = fmaf(a2.y, b4.w, acc[1][3]);
    }
    __syncthreads();
  }

  const float temp = temp_ptr[0];
  const uint32_t sk0 = SUBK.v[2 * t], sk1 = SUBK.v[2 * t + 1];
  const int nbase = n0 + tn * 4;
  unsigned long long bkey[2] = {0ull, 0ull};
#pragma unroll
  for (int i = 0; i < 2; ++i) {
    const int m = m0 + tm * 2 + i;
    float* rowp = out + ((size_t)m * T + t) * V_SZ;
    float yv[4];
#pragma unroll
    for (int j = 0; j < 4; ++j) {
      const int n = nbase + j;
      if (n < V_SZ) {
        const float logit = acc[i][j] + b_h2o[n];
        uint32_t r0, r1;
        threefry2x32(sk0, sk1, 0u, (uint32_t)(m * V_SZ + n), r0, r1);
        const uint32_t bits = r0 ^ r1;
        const float f = __uint_as_float((bits >> 9) | 0x3f800000u) - 1.0f;
        const float u = fmaxf(1e-20f, f + 1e-20f);
        const float gum = -logf(-logf(u));
        const float y = (logit + gum) / temp;
        yv[j] = y;
        uint32_t ub = __float_as_uint(y);
        ub = (ub & 0x80000000u) ? ~ub : (ub | 0x80000000u);
        const unsigned long long key =
            ((unsigned long long)ub << 32) | (unsigned long long)(~(uint32_t)n);
        if (key > bkey[i]) bkey[i] = key;
      } else {
        yv[j] = 0.f;
      }
    }
    if (nbase + 3 < V_SZ) {
      float4 v4; v4.x = yv[0]; v4.y = yv[1]; v4.z = yv[2]; v4.w = yv[3];
      *(float4*)&rowp[nbase] = v4;
    } else {
#pragma unroll
      for (int j = 0; j < 4; ++j)
        if (nbase + j < V_SZ) rowp[nbase + j] = yv[j];
    }
  }
#pragma unroll
  for (int mk = 1; mk < 16; mk <<= 1) {
#pragma unroll
    for (int i = 0; i < 2; ++i) {
      const unsigned long long o = __shfl_xor(bkey[i], mk);
      if (o > bkey[i]) bkey[i] = o;
    }
  }
  if (tn == 0) {
    unsigned long long* am = (unsigned long long*)(fws + AMX_OFF) + ((t & 1) ? 1024 : 0);
    atomicMax(&am[(m0 + tm * 2 + 0) * 8], bkey[0]);
    atomicMax(&am[(m0 + tm * 2 + 1) * 8], bkey[1]);
  }
}

// final: batched softmax normalization of all B*T rows (in place in out)
__global__ __launch_bounds__(256, 2) void k_soft(float* __restrict__ out, int T) {
  __shared__ float sy[V_SZ];
  __shared__ float red[256];
  const int bid = blockIdx.x;
  const int b = bid / T, t = bid - b * T;
  const int tid = threadIdx.x;
  float* row = out + ((size_t)b * T + t) * V_SZ;

  float lmax = -3.4e38f;
  for (int j = tid; j < V_SZ; j += 256) {
    const float y = row[j];
    sy[j] = y;
    lmax = fmaxf(lmax, y);
  }
  red[tid] = lmax; __syncthreads();
#pragma unroll
  for (int s = 128; s > 0; s >>= 1) {
    if (tid < s) red[tid] = fmaxf(red[tid], red[tid + s]);
    __syncthreads();
  }
  const float m = red[0];
  __syncthreads();

  float lsum = 0.f;
  for (int j = tid; j < V_SZ; j += 256) {
    const float e = expf(sy[j] - m); sy[j] = e; lsum += e;
  }
  red[tid] = lsum; __syncthreads();
#pragma unroll
  for (int s = 128; s > 0; s >>= 1) {
    if (tid < s) red[tid] += red[tid + s];
    __syncthreads();
  }
  const float S = red[0];
  __syncthreads();

  for (int j = tid; j < V_SZ; j += 256) row[j] = sy[j] / S;
}

// ---------------------------------------------------------------------------
extern "C" void kernel_launch(void* const* d_in, const int* in_sizes, int n_in,
                              void* d_out, int out_size, void* d_ws, size_t ws_size,
                              hipStream_t stream) {
  const float* z     = (const float*)d_in[0];
  const float* temp  = (const float*)d_in[1];
  const float* W_z2h = (const float*)d_in[3];
  const float* b_z2h = (const float*)d_in[4];
  const float* g1    = (const float*)d_in[5];
  const float* be1   = (const float*)d_in[6];
  const float* emb   = (const float*)d_in[7];
  const float* g2    = (const float*)d_in[8];
  const float* be2   = (const float*)d_in[9];
  const float* W_ih  = (const float*)d_in[10];
  const float* b_ih  = (const float*)d_in[11];
  const float* W_hh  = (const float*)d_in[12];
  const float* b_hh  = (const float*)d_in[13];
  const float* g3    = (const float*)d_in[14];
  const float* be3   = (const float*)d_in[15];
  const float* W_h2o = (const float*)d_in[16];
  const float* b_h2o = (const float*)d_in[17];
  float* out = (float*)d_out;
  float* fws = (float*)d_ws;
  const int T = out_size / (B_SZ * V_SZ);   // 128

  // ---- setup ----
  k_z2h<<<32, 256, 0, stream>>>(z, W_z2h, b_z2h, fws);
  k_bn1<<<64, 256, 0, stream>>>(g1, be1, fws);
  k_bn2<<<64, 256, 0, stream>>>(g2, be2, fws);
  k_setup4<<<193, 256, 0, stream>>>(W_ih, b_ih, W_hh, b_hh, fws);

  // ---- steps: 2 kernels each ----
  for (int t = 0; t < T; ++t) {
    k_gates<<<256, 512, 0, stream>>>(emb, g2, be2, W_ih, fws, t);
    k_logits_gh<<<412, 256, 0, stream>>>(W_h2o, b_h2o, W_hh, b_hh, g3, be3,
                                         temp, out, fws, t, T);
  }

  // ---- batched softmax normalization ----
  k_soft<<<B_SZ * T, 256, 0, stream>>>(out, T);
}